// Round 1
// baseline (436.563 us; speedup 1.0000x reference)
//
#include <hip/hip_runtime.h>
#include <math.h>

#define HD 4096  // H == D == 4096

// ---------------------------------------------------------------------------
// Kernel 1: fused 6-way GEMV + gate math.
// One wave (64 lanes) per output row; 4 waves (256 threads) per block.
// x is staged in LDS (16 KB). Each wave computes the 6 dot products for its
// row with float4 loads, reduces across lanes, then lane 0 applies the gate
// nonlinearities and writes per-row scalars.
// ---------------------------------------------------------------------------
__device__ __forceinline__ float row_dot(const float* __restrict__ W,
                                         const float4* __restrict__ xs4,
                                         int row, int lane) {
    const float4* Wrow = (const float4*)(W + (size_t)row * HD);
    float acc = 0.f;
#pragma unroll
    for (int t = 0; t < 16; ++t) {
        float4 w  = Wrow[t * 64 + lane];
        float4 xv = xs4[t * 64 + lane];
        acc += w.x * xv.x + w.y * xv.y + w.z * xv.z + w.w * xv.w;
    }
#pragma unroll
    for (int off = 32; off > 0; off >>= 1)
        acc += __shfl_xor(acc, off, 64);
    return acc;
}

__global__ __launch_bounds__(256) void k_gemv6(
    const float* __restrict__ x,
    const float* __restrict__ n_prev, const float* __restrict__ m_prev,
    const float* __restrict__ Wq, const float* __restrict__ bq,
    const float* __restrict__ Wk, const float* __restrict__ bk,
    const float* __restrict__ Wv, const float* __restrict__ bv,
    const float* __restrict__ Wi, const float* __restrict__ bi,
    const float* __restrict__ Wf, const float* __restrict__ bf,
    const float* __restrict__ Wo, const float* __restrict__ bo,
    float* __restrict__ ws_q, float* __restrict__ ws_v,
    float* __restrict__ ws_o, float* __restrict__ ws_fg,
    float* __restrict__ ws_ik,
    float* __restrict__ out_n, float* __restrict__ out_m)
{
    __shared__ float xs[HD];
    const int tid = threadIdx.x;
    {
        const float4* x4  = (const float4*)x;
        float4*       xs4 = (float4*)xs;
        for (int i = tid; i < HD / 4; i += 256) xs4[i] = x4[i];
    }
    __syncthreads();

    const int wave = tid >> 6;
    const int lane = tid & 63;
    const int row  = blockIdx.x * 4 + wave;
    const float4* xs4 = (const float4*)xs;

    float dq = row_dot(Wq, xs4, row, lane);
    float dk = row_dot(Wk, xs4, row, lane);
    float dv = row_dot(Wv, xs4, row, lane);
    float di = row_dot(Wi, xs4, row, lane);
    float df = row_dot(Wf, xs4, row, lane);
    float dо = row_dot(Wo, xs4, row, lane);

    if (lane == 0) {
        float q  = dq + bq[row];
        float k  = (dk + bk[row]) * (1.0f / 64.0f);  // 1/sqrt(4096)
        float v  = dv + bv[row];
        float it = di + bi[row];
        float ft = df + bf[row];
        float o  = 1.0f / (1.0f + expf(-(dо + bo[row])));
        float mp = m_prev[row];
        float mt = fmaxf(ft + mp, it);
        float ig = expf(it - mt);
        float fg = expf(ft + mp - mt);
        float nt = fg * n_prev[row] + ig * k;
        ws_q[row]  = q;
        ws_v[row]  = v;
        ws_o[row]  = o;
        ws_fg[row] = fg;
        ws_ik[row] = ig * k;
        out_n[row] = nt;
        out_m[row] = mt;
    }
}

// ---------------------------------------------------------------------------
// Kernel 2: denom = max(|n_t . q|, 1).  Single block.
// ---------------------------------------------------------------------------
__global__ __launch_bounds__(256) void k_denom(
    const float* __restrict__ out_n, const float* __restrict__ ws_q,
    float* __restrict__ denom)
{
    const int tid = threadIdx.x;
    float acc = 0.f;
    for (int i = tid; i < HD; i += 256) acc += out_n[i] * ws_q[i];
#pragma unroll
    for (int off = 32; off > 0; off >>= 1) acc += __shfl_xor(acc, off, 64);
    __shared__ float red[4];
    if ((tid & 63) == 0) red[tid >> 6] = acc;
    __syncthreads();
    if (tid == 0) {
        float s = red[0] + red[1] + red[2] + red[3];
        denom[0] = fmaxf(fabsf(s), 1.0f);
    }
}

// ---------------------------------------------------------------------------
// Kernel 3: c_t = f_g[c]*c_prev[r][c] + ik[c]*v[r]   (broadcast over LAST axis)
// fused with h_t[r] = o[r] * (c_t[r,:] . q) / denom.
// One block (256 threads) per row; float4 streaming.
// ---------------------------------------------------------------------------
__global__ __launch_bounds__(256) void k_ct(
    const float* __restrict__ c_prev,
    const float* __restrict__ ws_q, const float* __restrict__ ws_v,
    const float* __restrict__ ws_o, const float* __restrict__ ws_fg,
    const float* __restrict__ ws_ik, const float* __restrict__ denom,
    float* __restrict__ out_h, float* __restrict__ out_c)
{
    const int row = blockIdx.x;
    const int tid = threadIdx.x;
    const float vr = ws_v[row];

    const float4* cp4 = (const float4*)(c_prev + (size_t)row * HD);
    float4*       ct4 = (float4*)(out_c + (size_t)row * HD);
    const float4* fg4 = (const float4*)ws_fg;
    const float4* ik4 = (const float4*)ws_ik;
    const float4* q4  = (const float4*)ws_q;

    float acc = 0.f;
#pragma unroll
    for (int t = 0; t < 4; ++t) {
        const int idx = t * 256 + tid;
        float4 c  = cp4[idx];
        float4 f  = fg4[idx];
        float4 ik = ik4[idx];
        float4 qq = q4[idx];
        float4 ct;
        ct.x = f.x * c.x + ik.x * vr;
        ct.y = f.y * c.y + ik.y * vr;
        ct.z = f.z * c.z + ik.z * vr;
        ct.w = f.w * c.w + ik.w * vr;
        ct4[idx] = ct;
        acc += ct.x * qq.x + ct.y * qq.y + ct.z * qq.z + ct.w * qq.w;
    }
#pragma unroll
    for (int off = 32; off > 0; off >>= 1) acc += __shfl_xor(acc, off, 64);
    __shared__ float red[4];
    if ((tid & 63) == 0) red[tid >> 6] = acc;
    __syncthreads();
    if (tid == 0) {
        float s = red[0] + red[1] + red[2] + red[3];
        out_h[row] = ws_o[row] * s / denom[0];
    }
}

// ---------------------------------------------------------------------------
extern "C" void kernel_launch(void* const* d_in, const int* in_sizes, int n_in,
                              void* d_out, int out_size, void* d_ws, size_t ws_size,
                              hipStream_t stream) {
    const float* x      = (const float*)d_in[0];
    /* d_in[1] = h_prev: unused by the reference */
    const float* c_prev = (const float*)d_in[2];
    const float* n_prev = (const float*)d_in[3];
    const float* m_prev = (const float*)d_in[4];
    const float* Wq = (const float*)d_in[5];  const float* bq = (const float*)d_in[6];
    const float* Wk = (const float*)d_in[7];  const float* bk = (const float*)d_in[8];
    const float* Wv = (const float*)d_in[9];  const float* bv = (const float*)d_in[10];
    const float* Wi = (const float*)d_in[11]; const float* bi = (const float*)d_in[12];
    const float* Wf = (const float*)d_in[13]; const float* bf = (const float*)d_in[14];
    const float* Wo = (const float*)d_in[15]; const float* bo = (const float*)d_in[16];

    // Output layout: h_t [H], c_t [H,H], n_t [H], m_t [H] — flat concat.
    float* out   = (float*)d_out;
    float* out_h = out;
    float* out_c = out + HD;
    float* out_n = out + HD + (size_t)HD * HD;
    float* out_m = out_n + HD;

    // Workspace layout (floats): q, v, o, f_g, i_g*k, denom
    float* ws    = (float*)d_ws;
    float* ws_q  = ws;
    float* ws_v  = ws + 1 * HD;
    float* ws_o  = ws + 2 * HD;
    float* ws_fg = ws + 3 * HD;
    float* ws_ik = ws + 4 * HD;
    float* denom = ws + 5 * HD;

    k_gemv6<<<HD / 4, 256, 0, stream>>>(x, n_prev, m_prev,
                                        Wq, bq, Wk, bk, Wv, bv,
                                        Wi, bi, Wf, bf, Wo, bo,
                                        ws_q, ws_v, ws_o, ws_fg, ws_ik,
                                        out_n, out_m);
    k_denom<<<1, 256, 0, stream>>>(out_n, ws_q, denom);
    k_ct<<<HD, 256, 0, stream>>>(c_prev, ws_q, ws_v, ws_o, ws_fg, ws_ik,
                                 denom, out_h, out_c);
}